// Round 4
// baseline (288.683 us; speedup 1.0000x reference)
//
#include <hip/hip_runtime.h>
#include <hip/hip_bf16.h>

#define N_NODES 50000
#define N_EDGES 800000
#define NODE_F 128
#define EDGE_F 16
#define HID 64
#define N_ACT 6
#define NT_NODE (N_NODES / 16)   /* 3125 */
#define NT_EDGE (N_EDGES / 16)   /* 50000 */
#define NB_H 64                  /* histogram / fill slices */
#define SLICE (N_EDGES / NB_H)   /* 12500 */

typedef __bf16 bf16x8 __attribute__((ext_vector_type(8)));
typedef float f32x4 __attribute__((ext_vector_type(4)));

static __device__ __forceinline__ unsigned pk_bf16(float lo, float hi) {
    unsigned short a = __builtin_bit_cast(unsigned short, (__bf16)lo);
    unsigned short b = __builtin_bit_cast(unsigned short, (__bf16)hi);
    return (unsigned)a | ((unsigned)b << 16);
}
static __device__ __forceinline__ float blo(unsigned u) { return __uint_as_float(u << 16); }
static __device__ __forceinline__ float bhi(unsigned u) { return __uint_as_float(u & 0xffff0000u); }

// ================= Phase A: hist (wg-scope, block-private) || node GEMM || edge-head GEMM || edge-tail GEMM =================
#define A_GRID 1024
#define A_HIST 64
#define A_NODE_HI 394   /* 330 node blocks */
#define A_HEAD_HI 439   /* 45 head blocks; tail = 585 */
__launch_bounds__(256)
__global__ void k_pA(const int* __restrict__ ei, const float* __restrict__ x,
                     const float* __restrict__ ex, const float* __restrict__ Wn,
                     const float* __restrict__ We, const float* __restrict__ be,
                     unsigned* __restrict__ hist, unsigned* __restrict__ hb,
                     float* __restrict__ poolS) {
    const int bid = blockIdx.x, tid = threadIdx.x;
    if (bid < A_HIST) {
        // block-private histogram of dst over this block's edge slice; wg-scope -> XCD-L2 RMW
        unsigned* h = hist + (size_t)bid * N_NODES;
        const int jend = (bid + 1) * SLICE;
        for (int j = bid * SLICE + tid; j < jend; j += 256) {
            const int d = ei[N_EDGES + j];
            __hip_atomic_fetch_add(&h[d], 1u, __ATOMIC_RELAXED, __HIP_MEMORY_SCOPE_WORKGROUP);
        }
        return;
    }
    const int lane = tid & 63, wib = tid >> 6;
    const int g = lane >> 4, c = lane & 15;
    if (bid < A_NODE_HI) {
        // ---- node GEMM: hb[v] dwords 0..31 = bf16(node_x[v] @ Wn), UNSCALED ----
        bf16x8 bw[4][4];
#pragma unroll
        for (int s = 0; s < 4; ++s)
#pragma unroll
            for (int t = 0; t < 4; ++t) {
#pragma unroll
                for (int j = 0; j < 8; ++j)
                    bw[s][t][j] = (__bf16)Wn[(32 * s + 8 * g + j) * HID + t * 16 + c];
            }
        const int wv = (bid - A_HIST) * 4 + wib, nw = (A_NODE_HI - A_HIST) * 4;
        for (int tile = wv; tile < NT_NODE; tile += nw) {
            const int base = tile * 16;
            const int row = base + c;
            f32x4 acc0 = {}, acc1 = {}, acc2 = {}, acc3 = {};
#pragma unroll
            for (int s = 0; s < 4; ++s) {
                const float* p = x + (size_t)row * NODE_F + 32 * s + 8 * g;
                f32x4 v0 = *(const f32x4*)(p);
                f32x4 v1 = *(const f32x4*)(p + 4);
                bf16x8 a;
#pragma unroll
                for (int j = 0; j < 4; ++j) { a[j] = (__bf16)v0[j]; a[4 + j] = (__bf16)v1[j]; }
                acc0 = __builtin_amdgcn_mfma_f32_16x16x32_bf16(a, bw[s][0], acc0, 0, 0, 0);
                acc1 = __builtin_amdgcn_mfma_f32_16x16x32_bf16(a, bw[s][1], acc1, 0, 0, 0);
                acc2 = __builtin_amdgcn_mfma_f32_16x16x32_bf16(a, bw[s][2], acc2, 0, 0, 0);
                acc3 = __builtin_amdgcn_mfma_f32_16x16x32_bf16(a, bw[s][3], acc3, 0, 0, 0);
            }
#pragma unroll
            for (int q = 0; q < 4; ++q) {
                int i = base + 4 * g + q;
                hb[(size_t)i * 64 + c]      = pk_bf16(acc0[q], acc1[q]);
                hb[(size_t)i * 64 + 16 + c] = pk_bf16(acc2[q], acc3[q]);
            }
        }
        return;
    }
    // edge-GEMM weight fragments (head and tail)
    bf16x8 bw[4];
#pragma unroll
    for (int t = 0; t < 4; ++t) {
        bw[t] = bf16x8{};
        if (g < 2) {
#pragma unroll
            for (int j = 0; j < 8; ++j)
                bw[t][j] = (__bf16)We[(8 * g + j) * HID + t * 16 + c];
        }
    }
    if (bid < A_HEAD_HI) {
        // ---- edge-head GEMM: rows < N_NODES -> hb dwords 32..63, UNSCALED ----
        const int wv = (bid - A_NODE_HI) * 4 + wib, nw = (A_HEAD_HI - A_NODE_HI) * 4;
        for (int tile = wv; tile < NT_NODE; tile += nw) {
            const int base = tile * 16;
            bf16x8 a{};
            if (lane < 32) {
                const float* p = ex + (size_t)(base + c) * EDGE_F + 8 * g;
                f32x4 v0 = *(const f32x4*)(p);
                f32x4 v1 = *(const f32x4*)(p + 4);
#pragma unroll
                for (int j = 0; j < 4; ++j) { a[j] = (__bf16)v0[j]; a[4 + j] = (__bf16)v1[j]; }
            }
            f32x4 A0 = {}, A1 = {}, A2 = {}, A3 = {};
            A0 = __builtin_amdgcn_mfma_f32_16x16x32_bf16(a, bw[0], A0, 0, 0, 0);
            A1 = __builtin_amdgcn_mfma_f32_16x16x32_bf16(a, bw[1], A1, 0, 0, 0);
            A2 = __builtin_amdgcn_mfma_f32_16x16x32_bf16(a, bw[2], A2, 0, 0, 0);
            A3 = __builtin_amdgcn_mfma_f32_16x16x32_bf16(a, bw[3], A3, 0, 0, 0);
#pragma unroll
            for (int q = 0; q < 4; ++q) {
                int i = base + 4 * g + q;
                hb[(size_t)i * 64 + 32 + c] = pk_bf16(A0[q], A1[q]);
                hb[(size_t)i * 64 + 48 + c] = pk_bf16(A2[q], A3[q]);
            }
        }
        return;
    }
    // ---- edge-tail GEMM: rows >= N_NODES, deg==1 self-loop only -> relu(h+be) to pool ----
    const float be0 = be[c], be1 = be[16 + c], be2 = be[32 + c], be3 = be[48 + c];
    float pe0 = 0.f, pe1 = 0.f, pe2 = 0.f, pe3 = 0.f;
    const int wv = (bid - A_HEAD_HI) * 4 + wib, nw = (A_GRID - A_HEAD_HI) * 4;
    for (int t = NT_NODE + wv; t < NT_EDGE; t += nw) {
        const int base = t * 16;
        bf16x8 a{};
        if (lane < 32) {
            const float* p = ex + (size_t)(base + c) * EDGE_F + 8 * g;
            f32x4 v0 = *(const f32x4*)(p);
            f32x4 v1 = *(const f32x4*)(p + 4);
#pragma unroll
            for (int j = 0; j < 4; ++j) { a[j] = (__bf16)v0[j]; a[4 + j] = (__bf16)v1[j]; }
        }
        f32x4 A0 = {}, A1 = {}, A2 = {}, A3 = {};
        A0 = __builtin_amdgcn_mfma_f32_16x16x32_bf16(a, bw[0], A0, 0, 0, 0);
        A1 = __builtin_amdgcn_mfma_f32_16x16x32_bf16(a, bw[1], A1, 0, 0, 0);
        A2 = __builtin_amdgcn_mfma_f32_16x16x32_bf16(a, bw[2], A2, 0, 0, 0);
        A3 = __builtin_amdgcn_mfma_f32_16x16x32_bf16(a, bw[3], A3, 0, 0, 0);
#pragma unroll
        for (int q = 0; q < 4; ++q) {
            pe0 += fmaxf(A0[q] + be0, 0.f);
            pe1 += fmaxf(A1[q] + be1, 0.f);
            pe2 += fmaxf(A2[q] + be2, 0.f);
            pe3 += fmaxf(A3[q] + be3, 0.f);
        }
    }
#pragma unroll
    for (int off = 16; off < 64; off <<= 1) {
        pe0 += __shfl_xor(pe0, off);
        pe1 += __shfl_xor(pe1, off);
        pe2 += __shfl_xor(pe2, off);
        pe3 += __shfl_xor(pe3, off);
    }
    if (g == 0) {
        float* sh = poolS + (bid & 7) * 128;
        atomicAdd(&sh[64 + 2 * c], pe0);
        atomicAdd(&sh[65 + 2 * c], pe1);
        atomicAdd(&sh[96 + 2 * c], pe2);
        atomicAdd(&sh[97 + 2 * c], pe3);
    }
}

// ================= P1: merge hists -> cnt/dinv, block scan, global base via 1 atomic, rewrite hist into cursors =================
__global__ void k_p1(unsigned* __restrict__ hist, int* __restrict__ cnt,
                     float* __restrict__ dinv, int* __restrict__ start,
                     int* __restrict__ allocv) {
    __shared__ int sd[256];
    __shared__ int sbase;
    const int tid = threadIdx.x;
    const int i = blockIdx.x * 256 + tid;
    int v = 0;
    if (i < N_NODES) {
        unsigned s = 0;
#pragma unroll 8
        for (int b = 0; b < NB_H; ++b) s += hist[(size_t)b * N_NODES + i];
        v = (int)s;
        cnt[i] = v;
        dinv[i] = rsqrtf((float)v + 1.0f);
    }
    sd[tid] = v;
    __syncthreads();
    for (int off = 1; off < 256; off <<= 1) {
        int t = (tid >= off) ? sd[tid - off] : 0;
        __syncthreads();
        sd[tid] += t;
        __syncthreads();
    }
    if (tid == 255) sbase = atomicAdd(allocv, sd[255]);
    __syncthreads();
    const int st = sbase + sd[tid] - v; // exclusive + global base
    if (i < N_NODES) {
        start[i] = st;
        unsigned run = (unsigned)st;
        for (int b = 0; b < NB_H; ++b) {
            unsigned c = hist[(size_t)b * N_NODES + i];
            hist[(size_t)b * N_NODES + i] = run;
            run += c;
        }
    }
}

// ================= Fill: per-block cursors, wg-scope atomics (XCD-L2 RMW) =================
__launch_bounds__(1024)
__global__ void k_fill(const int* __restrict__ ei, unsigned* __restrict__ hist,
                       int* __restrict__ srcs) {
    const int b = blockIdx.x;
    unsigned* cur = hist + (size_t)b * N_NODES;
    const int jend = (b + 1) * SLICE;
    for (int j = b * SLICE + threadIdx.x; j < jend; j += 1024) {
        const int s = ei[j], d = ei[N_EDGES + j];
        const unsigned pos =
            __hip_atomic_fetch_add(&cur[d], 1u, __ATOMIC_RELAXED, __HIP_MEMORY_SCOPE_WORKGROUP);
        srcs[pos] = s;
    }
}

// ================= Gather: both convs + per-src dinv + relu + pool =================
#define P5_GRID 2048
__launch_bounds__(256)
__global__ void k_p5(const int* __restrict__ start, const int* __restrict__ cnt,
                     const int* __restrict__ srcs, const float* __restrict__ dinv,
                     const unsigned* __restrict__ hb, const float* __restrict__ bn,
                     const float* __restrict__ be, float* __restrict__ poolS) {
    const int tid = threadIdx.x;
    const int lane = tid & 63, wib = tid >> 6;
    const int p = lane & 31;
    const int col0 = (p < 16) ? p : p + 16;
    const float* bias = (lane < 32) ? bn : be;
    const float b0 = bias[col0], b1 = bias[col0 + 16];
    float p0 = 0.f, p1 = 0.f;
    const int wv = blockIdx.x * 4 + wib, nw = P5_GRID * 4;
    for (int v = wv; v < N_NODES; v += nw) {
        const int beg = start[v];
        const int dg = cnt[v];
        const float dv = dinv[v];
        const unsigned us = hb[(size_t)v * 64 + lane]; // self term, coeff dinv[v]
        float a0 = dv * blo(us), a1 = dv * bhi(us);
        float c0 = 0.f, c1 = 0.f, d0 = 0.f, d1 = 0.f, e0 = 0.f, e1 = 0.f;
        float f0 = 0.f, f1 = 0.f, g0 = 0.f, g1 = 0.f, h0 = 0.f, h1 = 0.f;
        float m0 = 0.f, m1 = 0.f, z0 = 0.f, z1 = 0.f;
        for (int bb = 0; bb < dg; bb += 64) {
            int rem = dg - bb;
            rem = (rem > 64) ? 64 : rem;
            const int sv = (lane < rem) ? srcs[beg + bb + lane] : 0;
            const unsigned fvb = __float_as_uint(dinv[sv]);
            int k = 0;
            for (; k + 7 < rem; k += 8) {
                const int i0 = __builtin_amdgcn_readlane(sv, k);
                const int i1 = __builtin_amdgcn_readlane(sv, k + 1);
                const int i2 = __builtin_amdgcn_readlane(sv, k + 2);
                const int i3 = __builtin_amdgcn_readlane(sv, k + 3);
                const int i4 = __builtin_amdgcn_readlane(sv, k + 4);
                const int i5 = __builtin_amdgcn_readlane(sv, k + 5);
                const int i6 = __builtin_amdgcn_readlane(sv, k + 6);
                const int i7 = __builtin_amdgcn_readlane(sv, k + 7);
                const float w0 = __uint_as_float(__builtin_amdgcn_readlane(fvb, k));
                const float w1 = __uint_as_float(__builtin_amdgcn_readlane(fvb, k + 1));
                const float w2 = __uint_as_float(__builtin_amdgcn_readlane(fvb, k + 2));
                const float w3 = __uint_as_float(__builtin_amdgcn_readlane(fvb, k + 3));
                const float w4 = __uint_as_float(__builtin_amdgcn_readlane(fvb, k + 4));
                const float w5 = __uint_as_float(__builtin_amdgcn_readlane(fvb, k + 5));
                const float w6 = __uint_as_float(__builtin_amdgcn_readlane(fvb, k + 6));
                const float w7 = __uint_as_float(__builtin_amdgcn_readlane(fvb, k + 7));
                const unsigned u0 = hb[(size_t)i0 * 64 + lane];
                const unsigned u1 = hb[(size_t)i1 * 64 + lane];
                const unsigned u2 = hb[(size_t)i2 * 64 + lane];
                const unsigned u3 = hb[(size_t)i3 * 64 + lane];
                const unsigned u4 = hb[(size_t)i4 * 64 + lane];
                const unsigned u5 = hb[(size_t)i5 * 64 + lane];
                const unsigned u6 = hb[(size_t)i6 * 64 + lane];
                const unsigned u7 = hb[(size_t)i7 * 64 + lane];
                a0 = fmaf(w0, blo(u0), a0); a1 = fmaf(w0, bhi(u0), a1);
                c0 = fmaf(w1, blo(u1), c0); c1 = fmaf(w1, bhi(u1), c1);
                d0 = fmaf(w2, blo(u2), d0); d1 = fmaf(w2, bhi(u2), d1);
                e0 = fmaf(w3, blo(u3), e0); e1 = fmaf(w3, bhi(u3), e1);
                f0 = fmaf(w4, blo(u4), f0); f1 = fmaf(w4, bhi(u4), f1);
                g0 = fmaf(w5, blo(u5), g0); g1 = fmaf(w5, bhi(u5), g1);
                h0 = fmaf(w6, blo(u6), h0); h1 = fmaf(w6, bhi(u6), h1);
                m0 = fmaf(w7, blo(u7), m0); m1 = fmaf(w7, bhi(u7), m1);
            }
            for (; k < rem; ++k) {
                const int i0 = __builtin_amdgcn_readlane(sv, k);
                const float w0 = __uint_as_float(__builtin_amdgcn_readlane(fvb, k));
                const unsigned u0 = hb[(size_t)i0 * 64 + lane];
                z0 = fmaf(w0, blo(u0), z0); z1 = fmaf(w0, bhi(u0), z1);
            }
        }
        const float S0 = (((a0 + c0) + (d0 + e0)) + ((f0 + g0) + (h0 + m0))) + z0;
        const float S1 = (((a1 + c1) + (d1 + e1)) + ((f1 + g1) + (h1 + m1))) + z1;
        p0 += fmaxf(fmaf(dv, S0, b0), 0.f);
        p1 += fmaxf(fmaf(dv, S1, b1), 0.f);
    }
    __shared__ float red[4][128];
    red[wib][2 * lane] = p0;
    red[wib][2 * lane + 1] = p1;
    __syncthreads();
    if (wib == 0) {
        float* sh = poolS + (blockIdx.x & 7) * 128;
        const float s0 = red[0][lane] + red[1][lane] + red[2][lane] + red[3][lane];
        const float s1 = red[0][lane + 64] + red[1][lane + 64] + red[2][lane + 64] + red[3][lane + 64];
        atomicAdd(&sh[lane], s0);
        atomicAdd(&sh[lane + 64], s1);
    }
}

// ================= Final: unpermute + means -> FC -> softmax =================
__global__ void k_p6(const float* __restrict__ poolS, const float* __restrict__ Wfc,
                     const float* __restrict__ bfc, float* __restrict__ out) {
    __shared__ float pool[128];
    __shared__ float logits[N_ACT];
    const int t = threadIdx.x; // 128 threads
    float s = 0.f;
    for (int sh = 0; sh < 8; ++sh) s += poolS[sh * 128 + t];
    const int half = t >> 6, r = t & 63, pp = r >> 1, slot = r & 1;
    const int col = ((pp < 16) ? pp : pp + 16) + 16 * slot + 64 * half;
    pool[col] = s * (half ? (1.0f / (float)N_EDGES) : (1.0f / (float)N_NODES));
    __syncthreads();
    if (t < N_ACT) {
        float acc = bfc[t];
        for (int k = 0; k < 128; ++k) acc = fmaf(pool[k], Wfc[k * N_ACT + t], acc);
        logits[t] = acc;
    }
    __syncthreads();
    if (t < N_ACT) {
        float m = logits[0];
        for (int a = 1; a < N_ACT; ++a) m = fmaxf(m, logits[a]);
        float sum = 0.f;
        for (int a = 0; a < N_ACT; ++a) sum += expf(logits[a] - m);
        out[t] = expf(logits[t] - m) / sum;
    }
}

extern "C" void kernel_launch(void* const* d_in, const int* in_sizes, int n_in,
                              void* d_out, int out_size, void* d_ws, size_t ws_size,
                              hipStream_t stream) {
    (void)in_sizes; (void)n_in; (void)out_size; (void)ws_size;
    const float* node_x = (const float*)d_in[0];
    const int*   ei     = (const int*)d_in[1];
    const float* edge_x = (const float*)d_in[2];
    const float* Wn     = (const float*)d_in[3];
    const float* bn     = (const float*)d_in[4];
    const float* We     = (const float*)d_in[5];
    const float* be     = (const float*)d_in[6];
    const float* Wfc    = (const float*)d_in[7];
    const float* bfc    = (const float*)d_in[8];
    float* out = (float*)d_out;

    // workspace layout (dwords)
    float*    ws     = (float*)d_ws;
    float*    poolS  = ws;                                  // 1024
    int*      allocv = (int*)(ws + 1024);                   // 16 (padded)
    unsigned* hist   = (unsigned*)(ws + 1040);              // NB_H * N_NODES = 3,200,000
    int*      cnt    = (int*)(hist + (size_t)NB_H * N_NODES);   // 50176
    int*      start  = cnt + 50176;                         // 50176
    float*    dinv   = (float*)(start + 50176);             // 50176
    int*      srcs   = (int*)(dinv + 50176);                // N_EDGES
    unsigned* hb     = (unsigned*)(srcs + N_EDGES);         // N_NODES * 64

    // zero: poolS + allocv + hist (12.8 MB)
    hipMemsetAsync(d_ws, 0, (size_t)(1040 + (size_t)NB_H * N_NODES) * 4, stream);

    k_pA  <<<A_GRID, 256, 0, stream>>>(ei, node_x, edge_x, Wn, We, be, hist, hb, poolS);
    k_p1  <<<196, 256, 0, stream>>>(hist, cnt, dinv, start, allocv);
    k_fill<<<NB_H, 1024, 0, stream>>>(ei, hist, srcs);
    k_p5  <<<P5_GRID, 256, 0, stream>>>(start, cnt, srcs, dinv, hb, bn, be, poolS);
    k_p6  <<<1, 128, 0, stream>>>(poolS, Wfc, bfc, out);
}

// Round 7
// 209.563 us; speedup vs baseline: 1.3775x; 1.3775x over previous
//
#include <hip/hip_runtime.h>
#include <hip/hip_bf16.h>

#define N_NODES 50000
#define N_EDGES 800000
#define NODE_F 128
#define EDGE_F 16
#define HID 64
#define N_ACT 6
#define NT_NODE (N_NODES / 16)   /* 3125 */
#define NT_EDGE (N_EDGES / 16)   /* 50000 */
#define NBKT 391                 /* ceil(50000/128) dst buckets */
#define NBLK_E 256               /* edge-slice blocks (cnt & bin) */
#define EPB (N_EDGES / NBLK_E)   /* 3125 edges per slice */
#define LCAP 4224                /* per-bucket LDS list capacity (mean 2048) */

typedef __bf16 bf16x8 __attribute__((ext_vector_type(8)));
typedef float f32x4 __attribute__((ext_vector_type(4)));

static __device__ __forceinline__ unsigned pk_bf16(float lo, float hi) {
    unsigned short a = __builtin_bit_cast(unsigned short, (__bf16)lo);
    unsigned short b = __builtin_bit_cast(unsigned short, (__bf16)hi);
    return (unsigned)a | ((unsigned)b << 16);
}
static __device__ __forceinline__ float blo(unsigned u) { return __uint_as_float(u << 16); }
static __device__ __forceinline__ float bhi(unsigned u) { return __uint_as_float(u & 0xffff0000u); }

// ================= Phase A: bucket-count || node GEMM || edge-head GEMM || edge-tail GEMM =================
#define A_CNT 256
#define A_NODE_HI (A_CNT + 330)    /* 586 */
#define A_HEAD_HI (A_NODE_HI + 45) /* 631 */
#define A_GRID 1216
__launch_bounds__(256)
__global__ void k_pA(const int* __restrict__ ei, const float* __restrict__ x,
                     const float* __restrict__ ex, const float* __restrict__ Wn,
                     const float* __restrict__ We, const float* __restrict__ be,
                     int* __restrict__ counts, unsigned* __restrict__ hb,
                     float* __restrict__ poolS) {
    const int bid = blockIdx.x, tid = threadIdx.x;
    if (bid < A_CNT) {
        // per-(block,bucket) edge counts via LDS histogram
        __shared__ int h[NBKT];
        for (int k = tid; k < NBKT; k += 256) h[k] = 0;
        __syncthreads();
        const int jend = (bid + 1) * EPB;
        for (int j = bid * EPB + tid; j < jend; j += 256)
            atomicAdd(&h[ei[N_EDGES + j] >> 7], 1);
        __syncthreads();
        for (int k = tid; k < NBKT; k += 256) counts[k * NBLK_E + bid] = h[k];
        return;
    }
    const int lane = tid & 63, wib = tid >> 6;
    const int g = lane >> 4, c = lane & 15;
    if (bid < A_NODE_HI) {
        // ---- node GEMM: hb[v] dwords 0..31 = bf16(node_x[v] @ Wn), UNSCALED ----
        bf16x8 bw[4][4];
#pragma unroll
        for (int s = 0; s < 4; ++s)
#pragma unroll
            for (int t = 0; t < 4; ++t) {
#pragma unroll
                for (int j = 0; j < 8; ++j)
                    bw[s][t][j] = (__bf16)Wn[(32 * s + 8 * g + j) * HID + t * 16 + c];
            }
        const int wv = (bid - A_CNT) * 4 + wib, nw = (A_NODE_HI - A_CNT) * 4;
        for (int tile = wv; tile < NT_NODE; tile += nw) {
            const int base = tile * 16;
            const int row = base + c;
            f32x4 acc0 = {}, acc1 = {}, acc2 = {}, acc3 = {};
#pragma unroll
            for (int s = 0; s < 4; ++s) {
                const float* p = x + (size_t)row * NODE_F + 32 * s + 8 * g;
                f32x4 v0 = *(const f32x4*)(p);
                f32x4 v1 = *(const f32x4*)(p + 4);
                bf16x8 a;
#pragma unroll
                for (int j = 0; j < 4; ++j) { a[j] = (__bf16)v0[j]; a[4 + j] = (__bf16)v1[j]; }
                acc0 = __builtin_amdgcn_mfma_f32_16x16x32_bf16(a, bw[s][0], acc0, 0, 0, 0);
                acc1 = __builtin_amdgcn_mfma_f32_16x16x32_bf16(a, bw[s][1], acc1, 0, 0, 0);
                acc2 = __builtin_amdgcn_mfma_f32_16x16x32_bf16(a, bw[s][2], acc2, 0, 0, 0);
                acc3 = __builtin_amdgcn_mfma_f32_16x16x32_bf16(a, bw[s][3], acc3, 0, 0, 0);
            }
#pragma unroll
            for (int q = 0; q < 4; ++q) {
                int i = base + 4 * g + q;
                hb[(size_t)i * 64 + c]      = pk_bf16(acc0[q], acc1[q]);
                hb[(size_t)i * 64 + 16 + c] = pk_bf16(acc2[q], acc3[q]);
            }
        }
        return;
    }
    bf16x8 bw[4];
#pragma unroll
    for (int t = 0; t < 4; ++t) {
        bw[t] = bf16x8{};
        if (g < 2) {
#pragma unroll
            for (int j = 0; j < 8; ++j)
                bw[t][j] = (__bf16)We[(8 * g + j) * HID + t * 16 + c];
        }
    }
    if (bid < A_HEAD_HI) {
        // ---- edge-head GEMM: rows < N_NODES -> hb dwords 32..63, UNSCALED ----
        const int wv = (bid - A_NODE_HI) * 4 + wib, nw = (A_HEAD_HI - A_NODE_HI) * 4;
        for (int tile = wv; tile < NT_NODE; tile += nw) {
            const int base = tile * 16;
            bf16x8 a{};
            if (lane < 32) {
                const float* p = ex + (size_t)(base + c) * EDGE_F + 8 * g;
                f32x4 v0 = *(const f32x4*)(p);
                f32x4 v1 = *(const f32x4*)(p + 4);
#pragma unroll
                for (int j = 0; j < 4; ++j) { a[j] = (__bf16)v0[j]; a[4 + j] = (__bf16)v1[j]; }
            }
            f32x4 A0 = {}, A1 = {}, A2 = {}, A3 = {};
            A0 = __builtin_amdgcn_mfma_f32_16x16x32_bf16(a, bw[0], A0, 0, 0, 0);
            A1 = __builtin_amdgcn_mfma_f32_16x16x32_bf16(a, bw[1], A1, 0, 0, 0);
            A2 = __builtin_amdgcn_mfma_f32_16x16x32_bf16(a, bw[2], A2, 0, 0, 0);
            A3 = __builtin_amdgcn_mfma_f32_16x16x32_bf16(a, bw[3], A3, 0, 0, 0);
#pragma unroll
            for (int q = 0; q < 4; ++q) {
                int i = base + 4 * g + q;
                hb[(size_t)i * 64 + 32 + c] = pk_bf16(A0[q], A1[q]);
                hb[(size_t)i * 64 + 48 + c] = pk_bf16(A2[q], A3[q]);
            }
        }
        return;
    }
    // ---- edge-tail GEMM: rows >= N_NODES, deg==1 self-loop only -> relu(h+be) to pool ----
    const float be0 = be[c], be1 = be[16 + c], be2 = be[32 + c], be3 = be[48 + c];
    float pe0 = 0.f, pe1 = 0.f, pe2 = 0.f, pe3 = 0.f;
    const int wv = (bid - A_HEAD_HI) * 4 + wib, nw = (A_GRID - A_HEAD_HI) * 4;
    for (int t = NT_NODE + wv; t < NT_EDGE; t += nw) {
        const int base = t * 16;
        bf16x8 a{};
        if (lane < 32) {
            const float* p = ex + (size_t)(base + c) * EDGE_F + 8 * g;
            f32x4 v0 = *(const f32x4*)(p);
            f32x4 v1 = *(const f32x4*)(p + 4);
#pragma unroll
            for (int j = 0; j < 4; ++j) { a[j] = (__bf16)v0[j]; a[4 + j] = (__bf16)v1[j]; }
        }
        f32x4 A0 = {}, A1 = {}, A2 = {}, A3 = {};
        A0 = __builtin_amdgcn_mfma_f32_16x16x32_bf16(a, bw[0], A0, 0, 0, 0);
        A1 = __builtin_amdgcn_mfma_f32_16x16x32_bf16(a, bw[1], A1, 0, 0, 0);
        A2 = __builtin_amdgcn_mfma_f32_16x16x32_bf16(a, bw[2], A2, 0, 0, 0);
        A3 = __builtin_amdgcn_mfma_f32_16x16x32_bf16(a, bw[3], A3, 0, 0, 0);
#pragma unroll
        for (int q = 0; q < 4; ++q) {
            pe0 += fmaxf(A0[q] + be0, 0.f);
            pe1 += fmaxf(A1[q] + be1, 0.f);
            pe2 += fmaxf(A2[q] + be2, 0.f);
            pe3 += fmaxf(A3[q] + be3, 0.f);
        }
    }
#pragma unroll
    for (int off = 16; off < 64; off <<= 1) {
        pe0 += __shfl_xor(pe0, off);
        pe1 += __shfl_xor(pe1, off);
        pe2 += __shfl_xor(pe2, off);
        pe3 += __shfl_xor(pe3, off);
    }
    if (g == 0) {
        float* sh = poolS + (bid & 7) * 128;
        atomicAdd(&sh[64 + 2 * c], pe0);
        atomicAdd(&sh[65 + 2 * c], pe1);
        atomicAdd(&sh[96 + 2 * c], pe2);
        atomicAdd(&sh[97 + 2 * c], pe3);
    }
}

// ================= scanB: per-bucket exclusive scan over block counts (in place) + totals =================
__global__ void k_scanB(int* __restrict__ counts, int* __restrict__ totals) {
    __shared__ int sd[NBLK_E];
    const int k = blockIdx.x, t = threadIdx.x;
    const int v = counts[k * NBLK_E + t];
    sd[t] = v;
    __syncthreads();
    for (int o = 1; o < NBLK_E; o <<= 1) {
        int a = (t >= o) ? sd[t - o] : 0;
        __syncthreads();
        sd[t] += a;
        __syncthreads();
    }
    counts[k * NBLK_E + t] = sd[t] - v;   // exclusive within bucket
    if (t == NBLK_E - 1) totals[k] = sd[t];
}

// ================= bin: scatter packed edges to dst-bucketed regions (LDS cursors only) =================
__launch_bounds__(256)
__global__ void k_bin(const int* __restrict__ ei, const int* __restrict__ offs,
                      const int* __restrict__ totals, int* __restrict__ gBases,
                      unsigned* __restrict__ ebin) {
    __shared__ int sA[256], sB[256];
    __shared__ int baseL[NBKT + 1];
    __shared__ int cur[NBKT];
    const int bid = blockIdx.x, t = threadIdx.x;
    const int v0 = totals[t];
    const int v1 = (256 + t < NBKT) ? totals[256 + t] : 0;
    sA[t] = v0; sB[t] = v1;
    __syncthreads();
    for (int o = 1; o < 256; o <<= 1) {
        int a = (t >= o) ? sA[t - o] : 0;
        int b = (t >= o) ? sB[t - o] : 0;
        __syncthreads();
        sA[t] += a; sB[t] += b;
        __syncthreads();
    }
    const int tot0 = sA[255];
    baseL[t] = sA[t] - v0;
    if (256 + t < NBKT) baseL[256 + t] = tot0 + sB[t] - v1;
    if (t == 0) baseL[NBKT] = tot0 + sB[NBKT - 256 - 1];
    __syncthreads();
    for (int k = t; k < NBKT; k += 256) cur[k] = baseL[k] + offs[k * NBLK_E + bid];
    if (bid == 0)
        for (int k = t; k < NBKT + 1; k += 256) gBases[k] = baseL[k];
    __syncthreads();
    const int jend = (bid + 1) * EPB;
    for (int j = bid * EPB + t; j < jend; j += 256) {
        const int s = ei[j], d = ei[N_EDGES + j];
        const int pos = atomicAdd(&cur[d >> 7], 1);
        ebin[pos] = ((unsigned)(d & 127) << 16) | (unsigned)s;
    }
}

// ================= dinv from binned edges =================
__global__ void k_dinv(const unsigned* __restrict__ ebin, const int* __restrict__ gBases,
                       float* __restrict__ dinv) {
    __shared__ int c[128];
    const int k = blockIdx.x, t = threadIdx.x;
    if (t < 128) c[t] = 0;
    __syncthreads();
    const int lo = gBases[k], hi = gBases[k + 1];
    for (int j = lo + t; j < hi; j += 256)
        atomicAdd(&c[(ebin[j] >> 16) & 127], 1);
    __syncthreads();
    if (t < 128) {
        const int v = k * 128 + t;
        if (v < N_NODES) dinv[v] = rsqrtf((float)c[t] + 1.0f);
    }
}

// ================= gather: CSR-in-LDS per bucket + both convs + relu + pool =================
__launch_bounds__(512)
__global__ void k_gather(const unsigned* __restrict__ ebin, const int* __restrict__ gBases,
                         const float* __restrict__ dinv, const unsigned* __restrict__ hb,
                         const float* __restrict__ bn, const float* __restrict__ be,
                         float* __restrict__ poolS) {
    __shared__ int cnts[128], off[128], cur[128];
    __shared__ unsigned short lists[LCAP];
    __shared__ float red[8][128];
    const int k = blockIdx.x, t = threadIdx.x;
    const int lane = t & 63, w = t >> 6;
    const int lo = gBases[k], ne = gBases[k + 1] - lo;
    if (t < 128) cnts[t] = 0;
    __syncthreads();
    for (int j = t; j < ne; j += 512)
        atomicAdd(&cnts[(ebin[lo + j] >> 16) & 127], 1);
    __syncthreads();
    if (t < 128) off[t] = cnts[t];
    __syncthreads();
    for (int o = 1; o < 128; o <<= 1) {
        int a = (t < 128 && t >= o) ? off[t - o] : 0;
        __syncthreads();
        if (t < 128) off[t] += a;
        __syncthreads();
    }
    if (t < 128) { const int ex = off[t] - cnts[t]; off[t] = ex; cur[t] = ex; }
    __syncthreads();
    for (int j = t; j < ne; j += 512) {
        const unsigned e = ebin[lo + j];
        const int pos = atomicAdd(&cur[(e >> 16) & 127], 1);
        if (pos < LCAP) lists[pos] = (unsigned short)(e & 0xFFFFu);
    }
    __syncthreads();

    const int p = lane & 31;
    const int col0 = (p < 16) ? p : p + 16;
    const float* bias = (lane < 32) ? bn : be;
    const float b0 = bias[col0], b1 = bias[col0 + 16];
    float p0 = 0.f, p1 = 0.f;
#pragma unroll
    for (int i = 0; i < 16; ++i) {
        const int dl = w + 8 * i;
        const int v = k * 128 + dl;
        if (v < N_NODES) {
            const float dv = dinv[v];
            const unsigned us = hb[(size_t)v * 64 + lane];
            float A0 = dv * blo(us), A1 = dv * bhi(us);
            float B0 = 0.f, B1 = 0.f, C0 = 0.f, C1 = 0.f, D0 = 0.f, D1 = 0.f;
            const int n = cnts[dl], b2 = off[dl];
            int kk = 0;
            for (; kk + 3 < n; kk += 4) {
                const int s0 = lists[b2 + kk], s1 = lists[b2 + kk + 1];
                const int s2 = lists[b2 + kk + 2], s3 = lists[b2 + kk + 3];
                const float w0 = dinv[s0], w1 = dinv[s1], w2 = dinv[s2], w3 = dinv[s3];
                const unsigned u0 = hb[(size_t)s0 * 64 + lane];
                const unsigned u1 = hb[(size_t)s1 * 64 + lane];
                const unsigned u2 = hb[(size_t)s2 * 64 + lane];
                const unsigned u3 = hb[(size_t)s3 * 64 + lane];
                A0 = fmaf(w0, blo(u0), A0); A1 = fmaf(w0, bhi(u0), A1);
                B0 = fmaf(w1, blo(u1), B0); B1 = fmaf(w1, bhi(u1), B1);
                C0 = fmaf(w2, blo(u2), C0); C1 = fmaf(w2, bhi(u2), C1);
                D0 = fmaf(w3, blo(u3), D0); D1 = fmaf(w3, bhi(u3), D1);
            }
            for (; kk < n; ++kk) {
                const int s0 = lists[b2 + kk];
                const float w0 = dinv[s0];
                const unsigned u0 = hb[(size_t)s0 * 64 + lane];
                A0 = fmaf(w0, blo(u0), A0); A1 = fmaf(w0, bhi(u0), A1);
            }
            const float S0 = (A0 + B0) + (C0 + D0);
            const float S1 = (A1 + B1) + (C1 + D1);
            p0 += fmaxf(fmaf(dv, S0, b0), 0.f);
            p1 += fmaxf(fmaf(dv, S1, b1), 0.f);
        }
    }
    red[w][2 * lane] = p0;
    red[w][2 * lane + 1] = p1;
    __syncthreads();
    if (w == 0) {
        float s0 = 0.f, s1 = 0.f;
#pragma unroll
        for (int r = 0; r < 8; ++r) { s0 += red[r][lane]; s1 += red[r][lane + 64]; }
        float* sh = poolS + (k & 7) * 128;
        atomicAdd(&sh[lane], s0);
        atomicAdd(&sh[lane + 64], s1);
    }
}

// ================= final: unpermute + means -> FC -> softmax =================
__global__ void k_p6(const float* __restrict__ poolS, const float* __restrict__ Wfc,
                     const float* __restrict__ bfc, float* __restrict__ out) {
    __shared__ float pool[128];
    __shared__ float logits[N_ACT];
    const int t = threadIdx.x; // 128 threads
    float s = 0.f;
    for (int sh = 0; sh < 8; ++sh) s += poolS[sh * 128 + t];
    const int half = t >> 6, r = t & 63, pp = r >> 1, slot = r & 1;
    const int col = ((pp < 16) ? pp : pp + 16) + 16 * slot + 64 * half;
    pool[col] = s * (half ? (1.0f / (float)N_EDGES) : (1.0f / (float)N_NODES));
    __syncthreads();
    if (t < N_ACT) {
        float acc = bfc[t];
        for (int k = 0; k < 128; ++k) acc = fmaf(pool[k], Wfc[k * N_ACT + t], acc);
        logits[t] = acc;
    }
    __syncthreads();
    if (t < N_ACT) {
        float m = logits[0];
        for (int a = 1; a < N_ACT; ++a) m = fmaxf(m, logits[a]);
        float sum = 0.f;
        for (int a = 0; a < N_ACT; ++a) sum += expf(logits[a] - m);
        out[t] = expf(logits[t] - m) / sum;
    }
}

extern "C" void kernel_launch(void* const* d_in, const int* in_sizes, int n_in,
                              void* d_out, int out_size, void* d_ws, size_t ws_size,
                              hipStream_t stream) {
    (void)in_sizes; (void)n_in; (void)out_size; (void)ws_size;
    const float* node_x = (const float*)d_in[0];
    const int*   ei     = (const int*)d_in[1];
    const float* edge_x = (const float*)d_in[2];
    const float* Wn     = (const float*)d_in[3];
    const float* bn     = (const float*)d_in[4];
    const float* We     = (const float*)d_in[5];
    const float* be     = (const float*)d_in[6];
    const float* Wfc    = (const float*)d_in[7];
    const float* bfc    = (const float*)d_in[8];
    float* out = (float*)d_out;

    // workspace layout (dwords)
    float*    ws     = (float*)d_ws;
    float*    poolS  = ws;                                    // 1024
    int*      counts = (int*)(ws + 1024);                     // NBKT*256 = 100096
    int*      totals = counts + NBKT * NBLK_E;                // 391 (+pad)
    int*      gBases = totals + 512;                          // 392 (+pad)
    unsigned* ebin   = (unsigned*)(gBases + 512);             // N_EDGES
    float*    dinv   = (float*)(ebin + N_EDGES);              // 50048
    unsigned* hb     = (unsigned*)(dinv + 50048);             // N_NODES * 64

    hipMemsetAsync(poolS, 0, 1024 * 4, stream);               // only the pool shards

    k_pA    <<<A_GRID, 256, 0, stream>>>(ei, node_x, edge_x, Wn, We, be, counts, hb, poolS);
    k_scanB <<<NBKT, NBLK_E, 0, stream>>>(counts, totals);
    k_bin   <<<NBLK_E, 256, 0, stream>>>(ei, counts, totals, gBases, ebin);
    k_dinv  <<<NBKT, 256, 0, stream>>>(ebin, gBases, dinv);
    k_gather<<<NBKT, 512, 0, stream>>>(ebin, gBases, dinv, hb, bn, be, poolS);
    k_p6    <<<1, 128, 0, stream>>>(poolS, Wfc, bfc, out);
}

// Round 8
// 205.765 us; speedup vs baseline: 1.4030x; 1.0185x over previous
//
#include <hip/hip_runtime.h>
#include <hip/hip_bf16.h>

#define N_NODES 50000
#define N_EDGES 800000
#define NODE_F 128
#define EDGE_F 16
#define HID 64
#define N_ACT 6
#define NT_NODE (N_NODES / 16)   /* 3125 */
#define NT_EDGE (N_EDGES / 16)   /* 50000 */
#define NBKT 782                 /* ceil(50000/64) dst buckets (64 dsts each) */
#define NBLK_E 256               /* edge-slice blocks (cnt & bin) */
#define EPB (N_EDGES / NBLK_E)   /* 3125 edges per slice */
#define LCAP 1536                /* per-bucket LDS list capacity (mean 1024, sigma 32) */

typedef __bf16 bf16x8 __attribute__((ext_vector_type(8)));
typedef float f32x4 __attribute__((ext_vector_type(4)));

static __device__ __forceinline__ unsigned pk_bf16(float lo, float hi) {
    unsigned short a = __builtin_bit_cast(unsigned short, (__bf16)lo);
    unsigned short b = __builtin_bit_cast(unsigned short, (__bf16)hi);
    return (unsigned)a | ((unsigned)b << 16);
}
static __device__ __forceinline__ float blo(unsigned u) { return __uint_as_float(u << 16); }
static __device__ __forceinline__ float bhi(unsigned u) { return __uint_as_float(u & 0xffff0000u); }

// ================= Phase A: bucket-count || node GEMM || edge-head GEMM || edge-tail GEMM =================
#define A_CNT 256
#define A_NODE_HI (A_CNT + 330)    /* 586 */
#define A_HEAD_HI (A_NODE_HI + 45) /* 631 */
#define A_GRID 1216
__launch_bounds__(256)
__global__ void k_pA(const int* __restrict__ ei, const float* __restrict__ x,
                     const float* __restrict__ ex, const float* __restrict__ Wn,
                     const float* __restrict__ We, const float* __restrict__ be,
                     int* __restrict__ counts, unsigned* __restrict__ hb,
                     float* __restrict__ poolS) {
    const int bid = blockIdx.x, tid = threadIdx.x;
    if (bid < A_CNT) {
        // per-(block,bucket) edge counts via LDS histogram
        __shared__ int h[NBKT];
        for (int k = tid; k < NBKT; k += 256) h[k] = 0;
        __syncthreads();
        const int jend = (bid + 1) * EPB;
        for (int j = bid * EPB + tid; j < jend; j += 256)
            atomicAdd(&h[ei[N_EDGES + j] >> 6], 1);
        __syncthreads();
        for (int k = tid; k < NBKT; k += 256) counts[k * NBLK_E + bid] = h[k];
        return;
    }
    const int lane = tid & 63, wib = tid >> 6;
    const int g = lane >> 4, c = lane & 15;
    if (bid < A_NODE_HI) {
        // ---- node GEMM: hb[v] dwords 0..31 = bf16(node_x[v] @ Wn), UNSCALED ----
        bf16x8 bw[4][4];
#pragma unroll
        for (int s = 0; s < 4; ++s)
#pragma unroll
            for (int t = 0; t < 4; ++t) {
#pragma unroll
                for (int j = 0; j < 8; ++j)
                    bw[s][t][j] = (__bf16)Wn[(32 * s + 8 * g + j) * HID + t * 16 + c];
            }
        const int wv = (bid - A_CNT) * 4 + wib, nw = (A_NODE_HI - A_CNT) * 4;
        for (int tile = wv; tile < NT_NODE; tile += nw) {
            const int base = tile * 16;
            const int row = base + c;
            f32x4 acc0 = {}, acc1 = {}, acc2 = {}, acc3 = {};
#pragma unroll
            for (int s = 0; s < 4; ++s) {
                const float* p = x + (size_t)row * NODE_F + 32 * s + 8 * g;
                f32x4 v0 = *(const f32x4*)(p);
                f32x4 v1 = *(const f32x4*)(p + 4);
                bf16x8 a;
#pragma unroll
                for (int j = 0; j < 4; ++j) { a[j] = (__bf16)v0[j]; a[4 + j] = (__bf16)v1[j]; }
                acc0 = __builtin_amdgcn_mfma_f32_16x16x32_bf16(a, bw[s][0], acc0, 0, 0, 0);
                acc1 = __builtin_amdgcn_mfma_f32_16x16x32_bf16(a, bw[s][1], acc1, 0, 0, 0);
                acc2 = __builtin_amdgcn_mfma_f32_16x16x32_bf16(a, bw[s][2], acc2, 0, 0, 0);
                acc3 = __builtin_amdgcn_mfma_f32_16x16x32_bf16(a, bw[s][3], acc3, 0, 0, 0);
            }
#pragma unroll
            for (int q = 0; q < 4; ++q) {
                int i = base + 4 * g + q;
                hb[(size_t)i * 64 + c]      = pk_bf16(acc0[q], acc1[q]);
                hb[(size_t)i * 64 + 16 + c] = pk_bf16(acc2[q], acc3[q]);
            }
        }
        return;
    }
    bf16x8 bw[4];
#pragma unroll
    for (int t = 0; t < 4; ++t) {
        bw[t] = bf16x8{};
        if (g < 2) {
#pragma unroll
            for (int j = 0; j < 8; ++j)
                bw[t][j] = (__bf16)We[(8 * g + j) * HID + t * 16 + c];
        }
    }
    if (bid < A_HEAD_HI) {
        // ---- edge-head GEMM: rows < N_NODES -> hb dwords 32..63, UNSCALED ----
        const int wv = (bid - A_NODE_HI) * 4 + wib, nw = (A_HEAD_HI - A_NODE_HI) * 4;
        for (int tile = wv; tile < NT_NODE; tile += nw) {
            const int base = tile * 16;
            bf16x8 a{};
            if (lane < 32) {
                const float* p = ex + (size_t)(base + c) * EDGE_F + 8 * g;
                f32x4 v0 = *(const f32x4*)(p);
                f32x4 v1 = *(const f32x4*)(p + 4);
#pragma unroll
                for (int j = 0; j < 4; ++j) { a[j] = (__bf16)v0[j]; a[4 + j] = (__bf16)v1[j]; }
            }
            f32x4 A0 = {}, A1 = {}, A2 = {}, A3 = {};
            A0 = __builtin_amdgcn_mfma_f32_16x16x32_bf16(a, bw[0], A0, 0, 0, 0);
            A1 = __builtin_amdgcn_mfma_f32_16x16x32_bf16(a, bw[1], A1, 0, 0, 0);
            A2 = __builtin_amdgcn_mfma_f32_16x16x32_bf16(a, bw[2], A2, 0, 0, 0);
            A3 = __builtin_amdgcn_mfma_f32_16x16x32_bf16(a, bw[3], A3, 0, 0, 0);
#pragma unroll
            for (int q = 0; q < 4; ++q) {
                int i = base + 4 * g + q;
                hb[(size_t)i * 64 + 32 + c] = pk_bf16(A0[q], A1[q]);
                hb[(size_t)i * 64 + 48 + c] = pk_bf16(A2[q], A3[q]);
            }
        }
        return;
    }
    // ---- edge-tail GEMM: rows >= N_NODES, deg==1 self-loop only -> relu(h+be) to pool ----
    const float be0 = be[c], be1 = be[16 + c], be2 = be[32 + c], be3 = be[48 + c];
    float pe0 = 0.f, pe1 = 0.f, pe2 = 0.f, pe3 = 0.f;
    const int wv = (bid - A_HEAD_HI) * 4 + wib, nw = (A_GRID - A_HEAD_HI) * 4;
    for (int t = NT_NODE + wv; t < NT_EDGE; t += nw) {
        const int base = t * 16;
        bf16x8 a{};
        if (lane < 32) {
            const float* p = ex + (size_t)(base + c) * EDGE_F + 8 * g;
            f32x4 v0 = *(const f32x4*)(p);
            f32x4 v1 = *(const f32x4*)(p + 4);
#pragma unroll
            for (int j = 0; j < 4; ++j) { a[j] = (__bf16)v0[j]; a[4 + j] = (__bf16)v1[j]; }
        }
        f32x4 A0 = {}, A1 = {}, A2 = {}, A3 = {};
        A0 = __builtin_amdgcn_mfma_f32_16x16x32_bf16(a, bw[0], A0, 0, 0, 0);
        A1 = __builtin_amdgcn_mfma_f32_16x16x32_bf16(a, bw[1], A1, 0, 0, 0);
        A2 = __builtin_amdgcn_mfma_f32_16x16x32_bf16(a, bw[2], A2, 0, 0, 0);
        A3 = __builtin_amdgcn_mfma_f32_16x16x32_bf16(a, bw[3], A3, 0, 0, 0);
#pragma unroll
        for (int q = 0; q < 4; ++q) {
            pe0 += fmaxf(A0[q] + be0, 0.f);
            pe1 += fmaxf(A1[q] + be1, 0.f);
            pe2 += fmaxf(A2[q] + be2, 0.f);
            pe3 += fmaxf(A3[q] + be3, 0.f);
        }
    }
#pragma unroll
    for (int off = 16; off < 64; off <<= 1) {
        pe0 += __shfl_xor(pe0, off);
        pe1 += __shfl_xor(pe1, off);
        pe2 += __shfl_xor(pe2, off);
        pe3 += __shfl_xor(pe3, off);
    }
    if (g == 0) {
        float* sh = poolS + (bid & 7) * 128;
        atomicAdd(&sh[64 + 2 * c], pe0);
        atomicAdd(&sh[65 + 2 * c], pe1);
        atomicAdd(&sh[96 + 2 * c], pe2);
        atomicAdd(&sh[97 + 2 * c], pe3);
    }
}

// ================= scanB: per-bucket exclusive scan over block counts (in place) + totals =================
__global__ void k_scanB(int* __restrict__ counts, int* __restrict__ totals) {
    __shared__ int sd[NBLK_E];
    const int k = blockIdx.x, t = threadIdx.x;
    const int v = counts[k * NBLK_E + t];
    sd[t] = v;
    __syncthreads();
    for (int o = 1; o < NBLK_E; o <<= 1) {
        int a = (t >= o) ? sd[t - o] : 0;
        __syncthreads();
        sd[t] += a;
        __syncthreads();
    }
    counts[k * NBLK_E + t] = sd[t] - v;   // exclusive within bucket
    if (t == NBLK_E - 1) totals[k] = sd[t];
}

// ================= bin: scatter packed edges to dst-bucketed regions (LDS cursors only) =================
__launch_bounds__(256)
__global__ void k_bin(const int* __restrict__ ei, const int* __restrict__ offs,
                      const int* __restrict__ totals, int* __restrict__ gBases,
                      unsigned* __restrict__ ebin) {
    __shared__ int sd[256];
    __shared__ int baseL[NBKT + 1];
    __shared__ int cur[NBKT];
    __shared__ int carrysh;
    const int bid = blockIdx.x, t = threadIdx.x;
    if (t == 0) carrysh = 0;
    __syncthreads();
#pragma unroll
    for (int ch = 0; ch < 4; ++ch) {            // 4*256 >= NBKT+1
        const int idx = ch * 256 + t;
        const int v = (idx < NBKT) ? totals[idx] : 0;
        const int carry = carrysh;
        sd[t] = v;
        __syncthreads();
        for (int o = 1; o < 256; o <<= 1) {
            int a = (t >= o) ? sd[t - o] : 0;
            __syncthreads();
            sd[t] += a;
            __syncthreads();
        }
        if (idx <= NBKT) baseL[idx] = carry + sd[t] - v;
        __syncthreads();
        if (t == 255) carrysh = carry + sd[255];
        __syncthreads();
    }
    for (int k = t; k < NBKT; k += 256) cur[k] = baseL[k] + offs[k * NBLK_E + bid];
    if (bid == 0)
        for (int k = t; k < NBKT + 1; k += 256) gBases[k] = baseL[k];
    __syncthreads();
    const int jend = (bid + 1) * EPB;
    for (int j = bid * EPB + t; j < jend; j += 256) {
        const int s = ei[j], d = ei[N_EDGES + j];
        const int pos = atomicAdd(&cur[d >> 6], 1);
        ebin[pos] = ((unsigned)(d & 63) << 16) | (unsigned)s;
    }
}

// ================= dinv + hb pre-scale (each block owns its bucket's 64 rows) =================
__launch_bounds__(256)
__global__ void k_dinvScale(const unsigned* __restrict__ ebin, const int* __restrict__ gBases,
                            float* __restrict__ dinv, unsigned* __restrict__ hb) {
    __shared__ int c[64];
    __shared__ float dvs[64];
    const int k = blockIdx.x, t = threadIdx.x;
    if (t < 64) c[t] = 0;
    __syncthreads();
    const int lo = gBases[k], hi = gBases[k + 1];
    for (int j = lo + t; j < hi; j += 256)
        atomicAdd(&c[(ebin[j] >> 16) & 63], 1);
    __syncthreads();
    if (t < 64) {
        const int v = k * 64 + t;
        if (v < N_NODES) {
            const float d = rsqrtf((float)c[t] + 1.0f);
            dinv[v] = d;
            dvs[t] = d;
        }
    }
    __syncthreads();
    // scale 64 rows x 64 dwords: 1024 dwordx4 chunks, 4 per thread
#pragma unroll
    for (int it = 0; it < 4; ++it) {
        const int chunk = t + 256 * it;
        const int r = chunk >> 4, q = chunk & 15;
        const int v = k * 64 + r;
        if (v < N_NODES) {
            const float d = dvs[r];
            unsigned* p = hb + (size_t)v * 64 + q * 4;
            uint4 u = *(uint4*)p;
            u.x = pk_bf16(d * blo(u.x), d * bhi(u.x));
            u.y = pk_bf16(d * blo(u.y), d * bhi(u.y));
            u.z = pk_bf16(d * blo(u.z), d * bhi(u.z));
            u.w = pk_bf16(d * blo(u.w), d * bhi(u.w));
            *(uint4*)p = u;
        }
    }
}

// ================= gather: CSR-in-LDS per bucket (64 dsts) + both convs + relu + pool =================
__launch_bounds__(512)
__global__ void k_gather(const unsigned* __restrict__ ebin, const int* __restrict__ gBases,
                         const float* __restrict__ dinv, const unsigned* __restrict__ hb,
                         const float* __restrict__ bn, const float* __restrict__ be,
                         float* __restrict__ poolS) {
    __shared__ int cnts[64], off[64], cur[64];
    __shared__ unsigned short lists[LCAP];
    __shared__ float red[8][128];
    const int k = blockIdx.x, t = threadIdx.x;
    const int lane = t & 63, w = t >> 6;
    const int lo = gBases[k], ne = gBases[k + 1] - lo;
    if (t < 64) cnts[t] = 0;
    __syncthreads();
    for (int j = t; j < ne; j += 512)
        atomicAdd(&cnts[(ebin[lo + j] >> 16) & 63], 1);
    __syncthreads();
    if (t < 64) off[t] = cnts[t];
    __syncthreads();
    for (int o = 1; o < 64; o <<= 1) {
        int a = (t < 64 && t >= o) ? off[t - o] : 0;
        __syncthreads();
        if (t < 64) off[t] += a;
        __syncthreads();
    }
    if (t < 64) { const int ex = off[t] - cnts[t]; off[t] = ex; cur[t] = ex; }
    __syncthreads();
    for (int j = t; j < ne; j += 512) {
        const unsigned e = ebin[lo + j];
        const int pos = atomicAdd(&cur[(e >> 16) & 63], 1);
        if (pos < LCAP) lists[pos] = (unsigned short)(e & 0xFFFFu);
    }
    __syncthreads();

    const int p = lane & 31;
    const int col0 = (p < 16) ? p : p + 16;
    const float* bias = (lane < 32) ? bn : be;
    const float b0 = bias[col0], b1 = bias[col0 + 16];
    float p0 = 0.f, p1 = 0.f;
#pragma unroll
    for (int i = 0; i < 8; ++i) {
        const int dl = w + 8 * i;
        const int v = k * 64 + dl;
        if (v < N_NODES) {
            const float dv = dinv[v];
            const unsigned us = hb[(size_t)v * 64 + lane]; // self term (pre-scaled)
            float A0 = blo(us), A1 = bhi(us);
            float B0 = 0.f, B1 = 0.f, C0 = 0.f, C1 = 0.f, D0 = 0.f, D1 = 0.f;
            const int n = cnts[dl], b2 = off[dl];
            int kk = 0;
            for (; kk + 3 < n; kk += 4) {
                const int s0 = lists[b2 + kk], s1 = lists[b2 + kk + 1];
                const int s2 = lists[b2 + kk + 2], s3 = lists[b2 + kk + 3];
                const unsigned u0 = hb[(size_t)s0 * 64 + lane];
                const unsigned u1 = hb[(size_t)s1 * 64 + lane];
                const unsigned u2 = hb[(size_t)s2 * 64 + lane];
                const unsigned u3 = hb[(size_t)s3 * 64 + lane];
                A0 += blo(u0); A1 += bhi(u0);
                B0 += blo(u1); B1 += bhi(u1);
                C0 += blo(u2); C1 += bhi(u2);
                D0 += blo(u3); D1 += bhi(u3);
            }
            for (; kk < n; ++kk) {
                const int s0 = lists[b2 + kk];
                const unsigned u0 = hb[(size_t)s0 * 64 + lane];
                A0 += blo(u0); A1 += bhi(u0);
            }
            const float S0 = (A0 + B0) + (C0 + D0);
            const float S1 = (A1 + B1) + (C1 + D1);
            p0 += fmaxf(fmaf(dv, S0, b0), 0.f);
            p1 += fmaxf(fmaf(dv, S1, b1), 0.f);
        }
    }
    red[w][2 * lane] = p0;
    red[w][2 * lane + 1] = p1;
    __syncthreads();
    if (w == 0) {
        float s0 = 0.f, s1 = 0.f;
#pragma unroll
        for (int r = 0; r < 8; ++r) { s0 += red[r][lane]; s1 += red[r][lane + 64]; }
        float* sh = poolS + (k & 7) * 128;
        atomicAdd(&sh[lane], s0);
        atomicAdd(&sh[lane + 64], s1);
    }
}

// ================= final: unpermute + means -> FC -> softmax =================
__global__ void k_p6(const float* __restrict__ poolS, const float* __restrict__ Wfc,
                     const float* __restrict__ bfc, float* __restrict__ out) {
    __shared__ float pool[128];
    __shared__ float logits[N_ACT];
    const int t = threadIdx.x; // 128 threads
    float s = 0.f;
    for (int sh = 0; sh < 8; ++sh) s += poolS[sh * 128 + t];
    const int half = t >> 6, r = t & 63, pp = r >> 1, slot = r & 1;
    const int col = ((pp < 16) ? pp : pp + 16) + 16 * slot + 64 * half;
    pool[col] = s * (half ? (1.0f / (float)N_EDGES) : (1.0f / (float)N_NODES));
    __syncthreads();
    if (t < N_ACT) {
        float acc = bfc[t];
        for (int k = 0; k < 128; ++k) acc = fmaf(pool[k], Wfc[k * N_ACT + t], acc);
        logits[t] = acc;
    }
    __syncthreads();
    if (t < N_ACT) {
        float m = logits[0];
        for (int a = 1; a < N_ACT; ++a) m = fmaxf(m, logits[a]);
        float sum = 0.f;
        for (int a = 0; a < N_ACT; ++a) sum += expf(logits[a] - m);
        out[t] = expf(logits[t] - m) / sum;
    }
}

extern "C" void kernel_launch(void* const* d_in, const int* in_sizes, int n_in,
                              void* d_out, int out_size, void* d_ws, size_t ws_size,
                              hipStream_t stream) {
    (void)in_sizes; (void)n_in; (void)out_size; (void)ws_size;
    const float* node_x = (const float*)d_in[0];
    const int*   ei     = (const int*)d_in[1];
    const float* edge_x = (const float*)d_in[2];
    const float* Wn     = (const float*)d_in[3];
    const float* bn     = (const float*)d_in[4];
    const float* We     = (const float*)d_in[5];
    const float* be     = (const float*)d_in[6];
    const float* Wfc    = (const float*)d_in[7];
    const float* bfc    = (const float*)d_in[8];
    float* out = (float*)d_out;

    // workspace layout (dwords)
    float*    ws     = (float*)d_ws;
    float*    poolS  = ws;                                    // 1024
    int*      counts = (int*)(ws + 1024);                     // NBKT*256 = 200192
    int*      totals = counts + NBKT * NBLK_E;                // 782 (+pad to 1024)
    int*      gBases = totals + 1024;                         // 783 (+pad to 1024)
    unsigned* ebin   = (unsigned*)(gBases + 1024);            // N_EDGES
    float*    dinv   = (float*)(ebin + N_EDGES);              // 50048
    unsigned* hb     = (unsigned*)(dinv + 50048);             // N_NODES * 64

    hipMemsetAsync(poolS, 0, 1024 * 4, stream);               // only the pool shards

    k_pA       <<<A_GRID, 256, 0, stream>>>(ei, node_x, edge_x, Wn, We, be, counts, hb, poolS);
    k_scanB    <<<NBKT, NBLK_E, 0, stream>>>(counts, totals);
    k_bin      <<<NBLK_E, 256, 0, stream>>>(ei, counts, totals, gBases, ebin);
    k_dinvScale<<<NBKT, 256, 0, stream>>>(ebin, gBases, dinv, hb);
    k_gather   <<<NBKT, 512, 0, stream>>>(ebin, gBases, dinv, hb, bn, be, poolS);
    k_p6       <<<1, 128, 0, stream>>>(poolS, Wfc, bfc, out);
}